// Round 1
// baseline (1480.216 us; speedup 1.0000x reference)
//
#include <hip/hip_runtime.h>

#define HWp (128*128)
#define Wd 128
#define Hd 128
#define K2 9
#define PIX 64
#define CH 8

// ---------------- Kernel A: offset = x . w_offset^T + b_offset ----------------
// offset[b,o,h,w] = sum_c x[b,c,h,w] * w_off[o,c] + b_off[o];  o in [0,72)
__global__ __launch_bounds__(256) void offset_kernel(
    const float* __restrict__ x, const float* __restrict__ w_off,
    const float* __restrict__ b_off, float* __restrict__ offs)
{
    __shared__ __align__(16) float wl[256 * 72];   // [c][o] layout, 73728 B
    int tid = threadIdx.x;
    for (int i = tid; i < 256 * 72; i += 256) {
        int o = i / 256, c = i % 256;
        wl[c * 72 + o] = w_off[i];
    }
    __syncthreads();
    int p = blockIdx.x * 256 + tid;          // global pixel id over B*H*W
    int b = p >> 14, pix = p & 16383;
    float acc[72];
    #pragma unroll
    for (int o = 0; o < 72; ++o) acc[o] = b_off[o];
    const float* xb = x + (size_t)b * 256 * HWp + pix;
    for (int c = 0; c < 256; ++c) {
        float xv = xb[(size_t)c * HWp];
        const float4* wp = (const float4*)&wl[c * 72];
        #pragma unroll
        for (int o4 = 0; o4 < 18; ++o4) {
            float4 wv = wp[o4];
            acc[o4*4+0] += xv * wv.x;
            acc[o4*4+1] += xv * wv.y;
            acc[o4*4+2] += xv * wv.z;
            acc[o4*4+3] += xv * wv.w;
        }
    }
    float* ob = offs + (size_t)b * 72 * HWp + pix;
    #pragma unroll
    for (int o = 0; o < 72; ++o) ob[(size_t)o * HWp] = acc[o];
}

// ---------------- Kernel B: fused deformable conv + ReLU ----------------
// Block: 256 threads, 64-pixel row tile. Thread owns output channel o = tid.
__global__ __launch_bounds__(256) void deform_kernel(
    const float* __restrict__ x, const float* __restrict__ offs,
    const float* __restrict__ wd, float* __restrict__ out)
{
    __shared__ int   c_yx[4 * K2 * PIX];                 // packed y0|x0 (int16)
    __shared__ float c_ly[4 * K2 * PIX];
    __shared__ float c_lx[4 * K2 * PIX];
    __shared__ __align__(16) float s_lds[CH * K2 * PIX]; // sampled values

    int tid = threadIdx.x;
    int gp0 = blockIdx.x * PIX;          // first pixel of tile (flat over B*H*W)
    int b   = gp0 >> 14;
    int hw0 = gp0 & 16383;
    int h   = hw0 >> 7;
    int w0  = hw0 & 127;

    // ---- per-tile bilinear coordinates: 4 groups * 9 taps * 64 pixels ----
    for (int i = tid; i < 4 * K2 * PIX; i += 256) {
        int g   = i / (K2 * PIX);
        int r   = i % (K2 * PIX);
        int tap = r / PIX;
        int p   = r % PIX;
        int chd = (g * K2 + tap) * 2;
        size_t obase = (size_t)(b * 72 + chd) * HWp + hw0 + p;
        float dy = offs[obase];
        float dx = offs[obase + HWp];
        float ys = (float)(h - 1 + tap / 3) + dy;
        float xs = (float)(w0 + p - 1 + tap % 3) + dx;
        float fy = floorf(ys), fx = floorf(xs);
        int y0 = (int)fy, x0 = (int)fx;
        c_ly[i] = ys - fy;
        c_lx[i] = xs - fx;
        c_yx[i] = (y0 & 0xffff) | (x0 << 16);
    }
    __syncthreads();

    float acc[PIX];
    #pragma unroll
    for (int p = 0; p < PIX; ++p) acc[p] = 0.f;

    const float* wg = wd + (size_t)tid * 256 * 9;   // this thread's output row

    for (int c0 = 0; c0 < 256; c0 += CH) {
        int g = c0 >> 6;                 // deform group (uniform over chunk)
        // ---- stage sampled[CH][9][PIX] into LDS: 4608 elems, 18/thread ----
        #pragma unroll
        for (int j = 0; j < (CH * K2 * PIX) / 256; ++j) {
            int e   = tid + j * 256;
            int ci  = e / (K2 * PIX);
            int r   = e % (K2 * PIX);
            int tap = r / PIX;
            int p   = r % PIX;
            int cidx = g * K2 * PIX + tap * PIX + p;
            int yx = c_yx[cidx];
            int y0 = (int)(short)(yx & 0xffff);
            int x0 = yx >> 16;
            float ly = c_ly[cidx], lx = c_lx[cidx];
            const float* xb = x + (size_t)(b * 256 + c0 + ci) * HWp;
            int y0c = min(max(y0, 0), Hd - 1), y1c = min(max(y0 + 1, 0), Hd - 1);
            int x0c = min(max(x0, 0), Wd - 1), x1c = min(max(x0 + 1, 0), Wd - 1);
            float v00 = xb[y0c * Wd + x0c];
            float v01 = xb[y0c * Wd + x1c];
            float v10 = xb[y1c * Wd + x0c];
            float v11 = xb[y1c * Wd + x1c];
            float vy0 = ((unsigned)y0       < 128u) ? 1.f : 0.f;
            float vy1 = ((unsigned)(y0 + 1) < 128u) ? 1.f : 0.f;
            float vx0 = ((unsigned)x0       < 128u) ? 1.f : 0.f;
            float vx1 = ((unsigned)(x0 + 1) < 128u) ? 1.f : 0.f;
            v00 *= vy0 * vx0; v01 *= vy0 * vx1;
            v10 *= vy1 * vx0; v11 *= vy1 * vx1;
            s_lds[e] = (1.f - ly) * (1.f - lx) * v00 + (1.f - ly) * lx * v01
                     + ly * (1.f - lx) * v10 + ly * lx * v11;
        }
        __syncthreads();
        // ---- accumulate: thread = output channel, 64 pixels ----
        for (int ci = 0; ci < CH; ++ci) {
            const float* wrow = wg + (size_t)(c0 + ci) * 9;
            #pragma unroll
            for (int tap = 0; tap < 9; ++tap) {
                float wv = wrow[tap];
                const float4* sp = (const float4*)&s_lds[ci * K2 * PIX + tap * PIX];
                #pragma unroll
                for (int p4 = 0; p4 < PIX / 4; ++p4) {
                    float4 sv = sp[p4];
                    acc[p4*4+0] += wv * sv.x;
                    acc[p4*4+1] += wv * sv.y;
                    acc[p4*4+2] += wv * sv.z;
                    acc[p4*4+3] += wv * sv.w;
                }
            }
        }
        __syncthreads();
    }

    float* ob = out + (size_t)(b * 256 + tid) * HWp + hw0;
    #pragma unroll
    for (int p4 = 0; p4 < PIX / 4; ++p4) {
        float4 v;
        v.x = fmaxf(acc[p4*4+0], 0.f);
        v.y = fmaxf(acc[p4*4+1], 0.f);
        v.z = fmaxf(acc[p4*4+2], 0.f);
        v.w = fmaxf(acc[p4*4+3], 0.f);
        ((float4*)ob)[p4] = v;
    }
}

extern "C" void kernel_launch(void* const* d_in, const int* in_sizes, int n_in,
                              void* d_out, int out_size, void* d_ws, size_t ws_size,
                              hipStream_t stream) {
    const float* x      = (const float*)d_in[0];   // [2,256,128,128]
    const float* w_off  = (const float*)d_in[1];   // [72,256,1,1]
    const float* b_off  = (const float*)d_in[2];   // [72]
    const float* w_def  = (const float*)d_in[3];   // [256,256,3,3]
    float* out  = (float*)d_out;
    float* offs = (float*)d_ws;                    // [2,72,128,128] = 9.4 MB

    // Kernel A: 32768 pixels / 256 = 128 blocks
    offset_kernel<<<128, 256, 0, stream>>>(x, w_off, b_off, offs);
    // Kernel B: 32768 pixels / 64 = 512 blocks
    deform_kernel<<<512, 256, 0, stream>>>(x, offs, w_def, out);
}

// Round 3
// 254.423 us; speedup vs baseline: 5.8179x; 5.8179x over previous
//
#include <hip/hip_runtime.h>

#define HW 16384

typedef __attribute__((ext_vector_type(4))) float f32x4;
typedef __attribute__((ext_vector_type(8))) short bf16x8;
typedef __attribute__((ext_vector_type(4))) int i32x4;

static __device__ __forceinline__ float bf2f(short s) {
    return __uint_as_float(((unsigned)(unsigned short)s) << 16);
}
static __device__ __forceinline__ unsigned short f2bf(float f) {
    unsigned u = __float_as_uint(f);
    unsigned r = u + 0x7fffu + ((u >> 16) & 1u);   // RNE (finite values)
    return (unsigned short)(r >> 16);
}

// ---------- transpose: x [2,256,128,128] f32 -> xT [2,16384,256] bf16 ----------
__global__ __launch_bounds__(256) void transpose_kernel(
    const float* __restrict__ x, unsigned short* __restrict__ xT)
{
    __shared__ float t[64][65];
    int bid = blockIdx.x;                 // 2048 = b(2) * pixtile(256) * ctile(4)
    int ct = bid & 3;
    int pt = (bid >> 2) & 255;
    int b  = bid >> 10;
    int l   = threadIdx.x & 63;
    int ci4 = threadIdx.x >> 6;
    const float* xb = x + ((size_t)(b * 256 + ct * 64)) * HW + pt * 64;
    for (int ci = ci4; ci < 64; ci += 4)
        t[ci][l] = xb[(size_t)ci * HW + l];
    __syncthreads();
    unsigned short* ob = xT + ((size_t)(b * HW + pt * 64)) * 256 + ct * 64;
    #pragma unroll
    for (int j = 0; j < 16; ++j) {
        int e = threadIdx.x + j * 256;
        int p = e >> 6, c = e & 63;
        ob[(size_t)p * 256 + c] = f2bf(t[c][p]);
    }
}

// ---------- weights: Wc[(g*9+tap)][o][cg] bf16 ; w_off -> bf16 ----------
__global__ __launch_bounds__(256) void convert_weights(
    const float* __restrict__ wd, const float* __restrict__ woff,
    unsigned short* __restrict__ Wc, unsigned short* __restrict__ woff_bf)
{
    int bid = blockIdx.x;
    if (bid < 576) {
        int t0 = (bid * 256 + threadIdx.x) * 4;
        #pragma unroll
        for (int r = 0; r < 4; ++r) {
            int ti = t0 + r;
            int cg = ti & 63;
            int o  = (ti >> 6) & 255;
            int kt = ti >> 14;              // 0..35 = g*9+tap
            int g = kt / 9, tap = kt - g * 9;
            Wc[ti] = f2bf(wd[(size_t)o * 2304 + (g * 64 + cg) * 9 + tap]);
        }
    } else {
        int e = (bid - 576) * 256 + threadIdx.x;   // 0..18431
        woff_bf[e] = f2bf(woff[e]);
    }
}

// ---------- main: fused offsets + deformable conv (MFMA) + ReLU ----------
// LDS: coords 2304*16=36864 | W_lds 32768 | S_lds 8192 ; xt(32768) aliases W_lds
__global__ __launch_bounds__(256, 2) void deform_kernel(
    const unsigned short* __restrict__ xT, const unsigned short* __restrict__ Wc,
    const unsigned short* __restrict__ woff_bf, const float* __restrict__ b_off,
    float* __restrict__ out)
{
    __shared__ __align__(16) char lds[77824];
    char* coordsB = lds;
    char* WldsB   = lds + 36864;
    char* SldsB   = lds + 69632;
    char* xtB     = lds + 36864;          // alias of W_lds (phase 1 only)

    const int t    = threadIdx.x;
    const int lane = t & 63;
    const int wave = t >> 6;
    const int bid  = blockIdx.x;
    const int gp0  = bid << 6;
    const int b    = gp0 >> 14;
    const int hw0  = gp0 & 16383;
    const int h    = hw0 >> 7;
    const int w0   = hw0 & 127;

    // ---- phase 0: stage x tile [64 pix][256 ch] bf16, swizzled ----
    {
        const i32x4* src = (const i32x4*)(xT + ((size_t)(b * HW + hw0)) * 256);
        i32x4* dst = (i32x4*)xtB;
        #pragma unroll
        for (int j = 0; j < 8; ++j) {
            int e = t + j * 256;
            int p = e >> 5, c16 = e & 31;
            dst[p * 32 + (c16 ^ (p & 31))] = src[e];
        }
    }
    __syncthreads();

    // ---- phase 1: offset dots + bilinear coords ----
    for (int j = 0; j < 9; ++j) {
        int i  = t + j * 256;             // 0..2303
        int gt = i >> 6;                  // g*9+tap (wave-uniform)
        int p  = i & 63;
        float ady = 0.f, adx = 0.f;
        const i32x4* wy = (const i32x4*)(woff_bf + (size_t)(gt * 2)     * 256);
        const i32x4* wx = (const i32x4*)(woff_bf + (size_t)(gt * 2 + 1) * 256);
        const i32x4* xr = (const i32x4*)xtB;
        for (int c16 = 0; c16 < 32; ++c16) {
            bf16x8 xv  = *(const bf16x8*)&xr[p * 32 + (c16 ^ (p & 31))];
            bf16x8 wyv = *(const bf16x8*)&wy[c16];
            bf16x8 wxv = *(const bf16x8*)&wx[c16];
            #pragma unroll
            for (int k = 0; k < 8; ++k) {
                float xf = bf2f(xv[k]);
                ady += xf * bf2f(wyv[k]);
                adx += xf * bf2f(wxv[k]);
            }
        }
        float dy = ady + b_off[gt * 2];
        float dx = adx + b_off[gt * 2 + 1];
        int ky = gt % 9 / 3;
        int kx = gt % 9 % 3;
        float ys = (float)(h - 1 + ky) + dy;
        float xs = (float)(w0 + p - 1 + kx) + dx;
        float fy = floorf(ys), fx = floorf(xs);
        int y0 = (int)fy, x0 = (int)fx;
        i32x4 st;
        st.x = (y0 & 0xffff) | (x0 << 16);
        st.y = __float_as_int(ys - fy);
        st.z = __float_as_int(xs - fx);
        st.w = 0;
        ((i32x4*)coordsB)[i] = st;
    }
    __syncthreads();

    f32x4 acc[4][4];
    #pragma unroll
    for (int mi = 0; mi < 4; ++mi)
        #pragma unroll
        for (int nj = 0; nj < 4; ++nj)
            acc[mi][nj] = (f32x4)0.f;

    const int p = lane;          // staging: pixel
    const int q = wave;          // staging: 16-channel slice / MFMA: o-block
    const int lr = lane & 15, lq = lane >> 4;

    for (int kc = 0; kc < 36; ++kc) {
        int g = kc / 9;
        // ---- stage W chunk [256 o][64 k] bf16, swizzled ----
        {
            const i32x4* src = (const i32x4*)(Wc + (size_t)kc * (256 * 64));
            i32x4* dst = (i32x4*)WldsB;
            #pragma unroll
            for (int j2 = 0; j2 < 8; ++j2) {
                int e = t + j2 * 256;
                int o = e >> 3, s = e & 7;
                dst[o * 8 + (s ^ (o & 7))] = src[e];
            }
        }
        // ---- build S chunk [64 pix][64 ch] bf16 via bilinear, swizzled ----
        {
            i32x4 cd = ((const i32x4*)coordsB)[kc * 64 + p];
            int yx = cd.x;
            int y0 = (int)(short)(yx & 0xffff);
            int x0 = yx >> 16;
            float ly = __int_as_float(cd.y);
            float lx = __int_as_float(cd.z);
            float vy0 = ((unsigned)y0       < 128u) ? 1.f : 0.f;
            float vy1 = ((unsigned)(y0 + 1) < 128u) ? 1.f : 0.f;
            float vx0 = ((unsigned)x0       < 128u) ? 1.f : 0.f;
            float vx1 = ((unsigned)(x0 + 1) < 128u) ? 1.f : 0.f;
            float w00 = (1.f - ly) * (1.f - lx) * vy0 * vx0;
            float w01 = (1.f - ly) * lx         * vy0 * vx1;
            float w10 = ly         * (1.f - lx) * vy1 * vx0;
            float w11 = ly         * lx         * vy1 * vx1;
            int y0c = min(max(y0, 0), 127), y1c = min(max(y0 + 1, 0), 127);
            int x0c = min(max(x0, 0), 127), x1c = min(max(x0 + 1, 0), 127);
            const unsigned short* base = xT + ((size_t)b * HW) * 256 + g * 64 + q * 16;
            const i32x4* c00 = (const i32x4*)(base + (y0c * 128 + x0c) * 256);
            const i32x4* c01 = (const i32x4*)(base + (y0c * 128 + x1c) * 256);
            const i32x4* c10 = (const i32x4*)(base + (y1c * 128 + x0c) * 256);
            const i32x4* c11 = (const i32x4*)(base + (y1c * 128 + x1c) * 256);
            i32x4* dst = (i32x4*)SldsB;
            #pragma unroll
            for (int u = 0; u < 2; ++u) {
                bf16x8 v00 = *(const bf16x8*)&c00[u];
                bf16x8 v01 = *(const bf16x8*)&c01[u];
                bf16x8 v10 = *(const bf16x8*)&c10[u];
                bf16x8 v11 = *(const bf16x8*)&c11[u];
                bf16x8 r;
                #pragma unroll
                for (int k2 = 0; k2 < 8; ++k2) {
                    float s = w00 * bf2f(v00[k2]) + w01 * bf2f(v01[k2])
                            + w10 * bf2f(v10[k2]) + w11 * bf2f(v11[k2]);
                    r[k2] = (short)f2bf(s);
                }
                dst[p * 8 + ((q * 2 + u) ^ (p & 7))] = *(const i32x4*)&r;
            }
        }
        __syncthreads();
        // ---- MFMA: D[o][pix], wave owns o in [q*64, q*64+64) ----
        {
            bf16x8 a[4][2], bb[4][2];
            #pragma unroll
            for (int mi = 0; mi < 4; ++mi)
                #pragma unroll
                for (int ks = 0; ks < 2; ++ks) {
                    int o = q * 64 + mi * 16 + lr;
                    a[mi][ks] = *(const bf16x8*)(WldsB + (size_t)(o * 8 + ((ks * 4 + lq) ^ (o & 7))) * 16);
                }
            #pragma unroll
            for (int nj = 0; nj < 4; ++nj)
                #pragma unroll
                for (int ks = 0; ks < 2; ++ks) {
                    int pp = nj * 16 + lr;
                    bb[nj][ks] = *(const bf16x8*)(SldsB + (size_t)(pp * 8 + ((ks * 4 + lq) ^ (pp & 7))) * 16);
                }
            #pragma unroll
            for (int ks = 0; ks < 2; ++ks)
                #pragma unroll
                for (int mi = 0; mi < 4; ++mi)
                    #pragma unroll
                    for (int nj = 0; nj < 4; ++nj)
                        acc[mi][nj] = __builtin_amdgcn_mfma_f32_16x16x32_bf16(
                            a[mi][ks], bb[nj][ks], acc[mi][nj], 0, 0, 0);
        }
        __syncthreads();
    }

    // ---- epilogue: ReLU + store (pixel-contiguous per 16 lanes) ----
    #pragma unroll
    for (int mi = 0; mi < 4; ++mi)
        #pragma unroll
        for (int nj = 0; nj < 4; ++nj)
            #pragma unroll
            for (int r = 0; r < 4; ++r) {
                int o  = q * 64 + mi * 16 + lq * 4 + r;
                int pp = nj * 16 + lr;
                out[((size_t)(b * 256 + o) << 14) + hw0 + pp] = fmaxf(acc[mi][nj][r], 0.f);
            }
}

extern "C" void kernel_launch(void* const* d_in, const int* in_sizes, int n_in,
                              void* d_out, int out_size, void* d_ws, size_t ws_size,
                              hipStream_t stream) {
    const float* x     = (const float*)d_in[0];   // [2,256,128,128]
    const float* w_off = (const float*)d_in[1];   // [72,256,1,1]
    const float* b_off = (const float*)d_in[2];   // [72]
    const float* w_def = (const float*)d_in[3];   // [256,256,3,3]
    float* out = (float*)d_out;

    unsigned short* xT      = (unsigned short*)d_ws;                     // 16.78 MB
    unsigned short* Wc      = (unsigned short*)((char*)d_ws + 16777216); // 1.18 MB
    unsigned short* woff_bf = (unsigned short*)((char*)d_ws + 17956864); // 36.9 KB

    transpose_kernel<<<2048, 256, 0, stream>>>(x, xT);
    convert_weights<<<648, 256, 0, stream>>>(w_def, w_off, Wc, woff_bf);
    deform_kernel<<<512, 256, 0, stream>>>(xT, Wc, woff_bf, b_off, out);
}

// Round 4
// 169.062 us; speedup vs baseline: 8.7555x; 1.5049x over previous
//
#include <hip/hip_runtime.h>

#define HW 16384

typedef __attribute__((ext_vector_type(4))) float f32x4;
typedef __attribute__((ext_vector_type(8))) short bf16x8;
typedef __attribute__((ext_vector_type(4))) int i32x4;

static __device__ __forceinline__ float bf2f(short s) {
    return __uint_as_float(((unsigned)(unsigned short)s) << 16);
}
static __device__ __forceinline__ unsigned short f2bf(float f) {
    unsigned u = __float_as_uint(f);
    unsigned r = u + 0x7fffu + ((u >> 16) & 1u);   // RNE
    return (unsigned short)(r >> 16);
}
static __device__ __forceinline__ int cvt_pk_bf16(float lo, float hi) {
    int r;
    asm("v_cvt_pk_bf16_f32 %0, %1, %2" : "=v"(r) : "v"(lo), "v"(hi));
    return r;
}

// ---------------- prep: transpose x -> NHWC bf16, weights -> fragment order ----------------
// blocks 0..2047:   xT[b][pix][ch] bf16
// blocks 2048..2335: Wc2 fragment-ordered deform weights
// blocks 2336..2345: Wo2[kk(8)][o(80 pad)][j(32)] offset weights
__global__ __launch_bounds__(256) void prep_kernel(
    const float* __restrict__ x, const float* __restrict__ wd,
    const float* __restrict__ woff,
    unsigned short* __restrict__ xT, unsigned short* __restrict__ Wc2,
    unsigned short* __restrict__ Wo2)
{
    int bid = blockIdx.x;
    int tid = threadIdx.x;
    if (bid < 2048) {
        __shared__ float tl[64][65];
        int ct = bid & 3, pt = (bid >> 2) & 255, b = bid >> 10;
        int l = tid & 63, ci4 = tid >> 6;
        const float* xb = x + ((size_t)(b * 256 + ct * 64)) * HW + pt * 64;
        for (int ci = ci4; ci < 64; ci += 4)
            tl[ci][l] = xb[(size_t)ci * HW + l];
        __syncthreads();
        unsigned short* ob = xT + ((size_t)(b * HW + pt * 64)) * 256 + ct * 64;
        #pragma unroll
        for (int j2 = 0; j2 < 2; ++j2) {
            int slot = tid + j2 * 256;       // 512 slots = 64 pix * 8 slices
            int p = slot >> 3, sl = slot & 7;
            i32x4 st;
            #pragma unroll
            for (int kq = 0; kq < 4; ++kq)
                ((int*)&st)[kq] = cvt_pk_bf16(tl[sl*8 + kq*2][p], tl[sl*8 + kq*2 + 1][p]);
            *(i32x4*)(ob + (size_t)p * 256 + sl * 8) = st;
        }
    } else if (bid < 2336) {
        // slot = kc*2048 + q*512 + mi*128 + ks*64 + lane ; 8 bf16 each
        int slot = (bid - 2048) * 256 + tid;     // 0..73727
        int l  = slot & 63;
        int ks = (slot >> 6) & 1;
        int mi = (slot >> 7) & 3;
        int q  = (slot >> 9) & 3;
        int kc = slot >> 11;                     // 0..35 = g*9+tap
        int g = kc / 9, tap = kc - g * 9;
        int o = q * 64 + mi * 16 + (l & 15);
        int cgb = (ks * 4 + (l >> 4)) * 8;
        unsigned short* dst = Wc2 + (size_t)slot * 8;
        const float* src = wd + (size_t)o * 2304 + tap;
        #pragma unroll
        for (int e = 0; e < 8; ++e)
            dst[e] = f2bf(src[(size_t)(g * 64 + cgb + e) * 9]);
    } else {
        int slot = (bid - 2336) * 256 + tid;     // 0..2559 b128 slots
        int kk = slot / 320;
        int rem = slot - kk * 320;
        int o = rem >> 2, jq = rem & 3;
        unsigned short* dst = Wo2 + (size_t)slot * 8;
        #pragma unroll
        for (int e = 0; e < 8; ++e)
            dst[e] = (o < 72) ? f2bf(woff[(size_t)o * 256 + kk * 32 + jq * 8 + e]) : (unsigned short)0;
    }
}

// ---------------- main: fused offsets (MFMA) + deformable conv (MFMA) + ReLU ----------------
__global__ __launch_bounds__(256, 3) void deform_kernel(
    const unsigned short* __restrict__ xT, const unsigned short* __restrict__ Wc2,
    const unsigned short* __restrict__ Wo2, const float* __restrict__ b_off,
    float* __restrict__ out)
{
    __shared__ int   c_yx[2304];
    __shared__ float c_ly[2304];
    __shared__ float c_lx[2304];
    __shared__ __align__(16) short Sl[4096];   // S tile [64 pix][64 ch] bf16, swizzled

    const int t    = threadIdx.x;
    const int lane = t & 63;
    const int q    = t >> 6;
    const int lr   = lane & 15, lq = lane >> 4;
    const int gp0  = blockIdx.x << 6;
    const int b    = gp0 >> 14;
    const int hw0  = gp0 & 16383;
    const int h    = hw0 >> 7;
    const int w0   = hw0 & 127;

    // ---- phase 1: 72 offset channels for this tile via MFMA ----
    {
        bf16x8 xb[8];
        const unsigned short* xrow = xT + ((size_t)(b * HW + hw0 + q * 16 + lr)) * 256 + lq * 8;
        #pragma unroll
        for (int kk = 0; kk < 8; ++kk)
            xb[kk] = *(const bf16x8*)(xrow + kk * 32);
        #pragma unroll
        for (int mi = 0; mi < 5; ++mi) {
            f32x4 oa = (f32x4)0.f;
            #pragma unroll
            for (int kk = 0; kk < 8; ++kk) {
                bf16x8 af = *(const bf16x8*)(Wo2 + (size_t)((kk * 80 + mi * 16 + lr) * 32 + lq * 8));
                oa = __builtin_amdgcn_mfma_f32_16x16x32_bf16(af, xb[kk], oa, 0, 0, 0);
            }
            #pragma unroll
            for (int ri = 0; ri < 2; ++ri) {
                int gt = mi * 8 + lq * 2 + ri;    // (g*9+tap), rows o=2gt (dy), 2gt+1 (dx)
                if (gt < 36) {
                    int p = q * 16 + lr;
                    float dy = oa[ri * 2]     + b_off[2 * gt];
                    float dx = oa[ri * 2 + 1] + b_off[2 * gt + 1];
                    int tap = gt % 9;
                    float ys = (float)(h - 1 + tap / 3) + dy;
                    float xs = (float)(w0 + p - 1 + tap % 3) + dx;
                    float fy = floorf(ys), fx = floorf(xs);
                    int y0 = (int)fy, x0 = (int)fx;
                    c_yx[gt * 64 + p] = (y0 & 0xffff) | (x0 << 16);
                    c_ly[gt * 64 + p] = ys - fy;
                    c_lx[gt * 64 + p] = xs - fx;
                }
            }
        }
    }
    __syncthreads();

    f32x4 acc[4][4];
    #pragma unroll
    for (int mi = 0; mi < 4; ++mi)
        #pragma unroll
        for (int nj = 0; nj < 4; ++nj)
            acc[mi][nj] = (f32x4)0.f;

    const unsigned short* xbase = xT + ((size_t)b * HW) * 256;

    for (int g = 0; g < 4; ++g)
    for (int tap = 0; tap < 9; ++tap) {
        const int kc = g * 9 + tap;
        // ---- A-fragments straight from global (fragment-ordered, L2-hot) ----
        bf16x8 a_[4][2];
        {
            const unsigned short* wb = Wc2 + (size_t)(kc * 16 + q * 4) * 1024 + lane * 8;
            #pragma unroll
            for (int mi = 0; mi < 4; ++mi)
                #pragma unroll
                for (int ks = 0; ks < 2; ++ks)
                    a_[mi][ks] = *(const bf16x8*)(wb + mi * 1024 + ks * 512);
        }
        // ---- build S tile: wave q -> pixels [q*16, q*16+16), lanes = 8 pix x 8 slices ----
        #pragma unroll
        for (int pg = 0; pg < 2; ++pg) {
            int p   = q * 16 + pg * 8 + (lane >> 3);
            int sl  = lane & 7;
            int idx = kc * 64 + p;
            int yx = c_yx[idx];
            int y0 = (int)(short)(yx & 0xffff);
            int x0 = yx >> 16;
            float ly = c_ly[idx], lx = c_lx[idx];
            float omy = 1.f - ly, omx = 1.f - lx;
            float vy0 = ((unsigned)y0       < 128u) ? 1.f : 0.f;
            float vy1 = ((unsigned)(y0 + 1) < 128u) ? 1.f : 0.f;
            float vx0 = ((unsigned)x0       < 128u) ? 1.f : 0.f;
            float vx1 = ((unsigned)(x0 + 1) < 128u) ? 1.f : 0.f;
            float w00 = omy * omx * vy0 * vx0, w01 = omy * lx * vy0 * vx1;
            float w10 = ly  * omx * vy1 * vx0, w11 = ly  * lx * vy1 * vx1;
            int y0c = min(max(y0, 0), 127), y1c = min(max(y0 + 1, 0), 127);
            int x0c = min(max(x0, 0), 127), x1c = min(max(x0 + 1, 0), 127);
            const unsigned short* cb = xbase + (size_t)(g * 64 + sl * 8);
            bf16x8 v00 = *(const bf16x8*)(cb + (size_t)(y0c * 128 + x0c) * 256);
            bf16x8 v01 = *(const bf16x8*)(cb + (size_t)(y0c * 128 + x1c) * 256);
            bf16x8 v10 = *(const bf16x8*)(cb + (size_t)(y1c * 128 + x0c) * 256);
            bf16x8 v11 = *(const bf16x8*)(cb + (size_t)(y1c * 128 + x1c) * 256);
            float sv[8];
            #pragma unroll
            for (int e = 0; e < 8; ++e)
                sv[e] = w00 * bf2f(v00[e]) + w01 * bf2f(v01[e])
                      + w10 * bf2f(v10[e]) + w11 * bf2f(v11[e]);
            i32x4 st;
            #pragma unroll
            for (int kq = 0; kq < 4; ++kq)
                ((int*)&st)[kq] = cvt_pk_bf16(sv[kq * 2], sv[kq * 2 + 1]);
            ((i32x4*)Sl)[p * 8 + (sl ^ (p & 7))] = st;
        }
        __syncthreads();
        // ---- MFMA: D[o][pix] ----
        #pragma unroll
        for (int ks = 0; ks < 2; ++ks) {
            bf16x8 bb[4];
            #pragma unroll
            for (int nj = 0; nj < 4; ++nj) {
                int pp = nj * 16 + lr;
                bb[nj] = *(const bf16x8*)&((const i32x4*)Sl)[pp * 8 + ((ks * 4 + lq) ^ (pp & 7))];
            }
            #pragma unroll
            for (int mi = 0; mi < 4; ++mi)
                #pragma unroll
                for (int nj = 0; nj < 4; ++nj)
                    acc[mi][nj] = __builtin_amdgcn_mfma_f32_16x16x32_bf16(
                        a_[mi][ks], bb[nj], acc[mi][nj], 0, 0, 0);
        }
        __syncthreads();
    }

    // ---- epilogue: ReLU + store ----
    #pragma unroll
    for (int mi = 0; mi < 4; ++mi)
        #pragma unroll
        for (int nj = 0; nj < 4; ++nj)
            #pragma unroll
            for (int r = 0; r < 4; ++r) {
                int o  = q * 64 + mi * 16 + lq * 4 + r;
                int pp = nj * 16 + lr;
                out[((size_t)(b * 256 + o) << 14) + hw0 + pp] = fmaxf(acc[mi][nj][r], 0.f);
            }
}

extern "C" void kernel_launch(void* const* d_in, const int* in_sizes, int n_in,
                              void* d_out, int out_size, void* d_ws, size_t ws_size,
                              hipStream_t stream) {
    const float* x     = (const float*)d_in[0];   // [2,256,128,128]
    const float* w_off = (const float*)d_in[1];   // [72,256,1,1]
    const float* b_off = (const float*)d_in[2];   // [72]
    const float* w_def = (const float*)d_in[3];   // [256,256,3,3]
    float* out = (float*)d_out;

    unsigned short* xT  = (unsigned short*)d_ws;                     // 16.78 MB
    unsigned short* Wc2 = (unsigned short*)((char*)d_ws + 16777216); // 1.18 MB
    unsigned short* Wo2 = (unsigned short*)((char*)d_ws + 17956864); // 40 KB

    prep_kernel<<<2346, 256, 0, stream>>>(x, w_def, w_off, xT, Wc2, Wo2);
    deform_kernel<<<512, 256, 0, stream>>>(xT, Wc2, Wo2, b_off, out);
}

// Round 5
// 162.428 us; speedup vs baseline: 9.1131x; 1.0408x over previous
//
#include <hip/hip_runtime.h>

#define HW 16384

typedef __attribute__((ext_vector_type(4))) float f32x4;
typedef __attribute__((ext_vector_type(8))) short bf16x8;
typedef __attribute__((ext_vector_type(4))) int i32x4;

static __device__ __forceinline__ float bf2f(short s) {
    return __uint_as_float(((unsigned)(unsigned short)s) << 16);
}
static __device__ __forceinline__ unsigned short f2bf(float f) {
    unsigned u = __float_as_uint(f);
    unsigned r = u + 0x7fffu + ((u >> 16) & 1u);   // RNE
    return (unsigned short)(r >> 16);
}
static __device__ __forceinline__ int cvt_pk_bf16(float lo, float hi) {
    int r;
    asm("v_cvt_pk_bf16_f32 %0, %1, %2" : "=v"(r) : "v"(lo), "v"(hi));
    return r;
}

// ---------------- prep: transpose x -> NHWC bf16, weights -> fragment order ----------------
__global__ __launch_bounds__(256) void prep_kernel(
    const float* __restrict__ x, const float* __restrict__ wd,
    const float* __restrict__ woff,
    unsigned short* __restrict__ xT, unsigned short* __restrict__ Wc2,
    unsigned short* __restrict__ Wo2)
{
    int bid = blockIdx.x;
    int tid = threadIdx.x;
    if (bid < 2048) {
        __shared__ float tl[64][65];
        int ct = bid & 3, pt = (bid >> 2) & 255, b = bid >> 10;
        const float* xb = x + ((size_t)(b * 256 + ct * 64)) * HW + pt * 64;
        #pragma unroll
        for (int j = 0; j < 4; ++j) {
            int slot = tid + j * 256;            // 1024 = 64 ch * 16 quads
            int c = slot >> 4, p4 = slot & 15;
            float4 v = *(const float4*)(xb + (size_t)c * HW + p4 * 4);
            tl[c][p4 * 4 + 0] = v.x;
            tl[c][p4 * 4 + 1] = v.y;
            tl[c][p4 * 4 + 2] = v.z;
            tl[c][p4 * 4 + 3] = v.w;
        }
        __syncthreads();
        unsigned short* ob = xT + ((size_t)(b * HW + pt * 64)) * 256 + ct * 64;
        #pragma unroll
        for (int j2 = 0; j2 < 2; ++j2) {
            int slot = tid + j2 * 256;           // 512 = 64 pix * 8 slices
            int p = slot >> 3, sl = slot & 7;
            i32x4 st;
            #pragma unroll
            for (int kq = 0; kq < 4; ++kq)
                ((int*)&st)[kq] = cvt_pk_bf16(tl[sl*8 + kq*2][p], tl[sl*8 + kq*2 + 1][p]);
            *(i32x4*)(ob + (size_t)p * 256 + sl * 8) = st;
        }
    } else if (bid < 2336) {
        // slot = kc*2048 + q4*512 + mi*128 + ks*64 + lane ; 8 bf16 each
        int slot = (bid - 2048) * 256 + tid;     // 0..73727
        int l  = slot & 63;
        int ks = (slot >> 6) & 1;
        int mi = (slot >> 7) & 3;
        int q4 = (slot >> 9) & 3;
        int kc = slot >> 11;                     // 0..35 = g*9+tap
        int g = kc / 9, tap = kc - g * 9;
        int o = q4 * 64 + mi * 16 + (l & 15);
        int cgb = (ks * 4 + (l >> 4)) * 8;
        unsigned short* dst = Wc2 + (size_t)slot * 8;
        const float* src = wd + (size_t)o * 2304 + tap;
        #pragma unroll
        for (int e = 0; e < 8; ++e)
            dst[e] = f2bf(src[(size_t)(g * 64 + cgb + e) * 9]);
    } else {
        int slot = (bid - 2336) * 256 + tid;     // 0..2559 b128 slots
        int kk = slot / 320;
        int rem = slot - kk * 320;
        int o = rem >> 2, jq = rem & 3;
        unsigned short* dst = Wo2 + (size_t)slot * 8;
        #pragma unroll
        for (int e = 0; e < 8; ++e)
            dst[e] = (o < 72) ? f2bf(woff[(size_t)o * 256 + kk * 32 + jq * 8 + e]) : (unsigned short)0;
    }
}

// ---------------- main: fused offsets (MFMA) + deformable conv (MFMA, pipelined) + ReLU ----------------
__global__ __launch_bounds__(512, 4) void deform_kernel(
    const unsigned short* __restrict__ xT, const unsigned short* __restrict__ Wc2,
    const unsigned short* __restrict__ Wo2, const float* __restrict__ b_off,
    float* __restrict__ out)
{
    __shared__ int   c_yx[2304];
    __shared__ float c_ly[2304];
    __shared__ float c_lx[2304];
    __shared__ __align__(16) short Sbuf[2][4096];   // double-buffered S tile [64 pix][64 ch]

    const int t    = threadIdx.x;
    const int lane = t & 63;
    const int q    = t >> 6;                 // wave 0..7
    const int lr   = lane & 15, lq = lane >> 4;
    int bid = blockIdx.x;
    bid = (bid & 7) * 64 + (bid >> 3);       // XCD-aware swizzle (512 % 8 == 0)
    const int gp0  = bid << 6;
    const int b    = gp0 >> 14;
    const int hw0  = gp0 & 16383;
    const int h    = hw0 >> 7;
    const int w0   = hw0 & 127;

    // ---- phase 1: 72 offset channels via MFMA (waves 0-3: mi 0..2, waves 4-7: mi 3..4) ----
    {
        const int p16 = (q & 3) * 16;
        bf16x8 xv[8];
        const unsigned short* xrow = xT + ((size_t)(b * HW + hw0 + p16 + lr)) * 256 + lq * 8;
        #pragma unroll
        for (int kk = 0; kk < 8; ++kk)
            xv[kk] = *(const bf16x8*)(xrow + kk * 32);
        const int mi0 = (q < 4) ? 0 : 3;
        const int nmi = (q < 4) ? 3 : 2;
        for (int im = 0; im < nmi; ++im) {
            int mi = mi0 + im;
            f32x4 oa = (f32x4)0.f;
            #pragma unroll
            for (int kk = 0; kk < 8; ++kk) {
                bf16x8 af = *(const bf16x8*)(Wo2 + (size_t)((kk * 80 + mi * 16 + lr) * 32 + lq * 8));
                oa = __builtin_amdgcn_mfma_f32_16x16x32_bf16(af, xv[kk], oa, 0, 0, 0);
            }
            #pragma unroll
            for (int ri = 0; ri < 2; ++ri) {
                int gt = mi * 8 + lq * 2 + ri;
                if (gt < 36) {
                    int p = p16 + lr;
                    float dy = oa[ri * 2]     + b_off[2 * gt];
                    float dx = oa[ri * 2 + 1] + b_off[2 * gt + 1];
                    int tap = gt % 9;
                    float ys = (float)(h - 1 + tap / 3) + dy;
                    float xs = (float)(w0 + p - 1 + tap % 3) + dx;
                    float fy = floorf(ys), fx = floorf(xs);
                    c_yx[gt * 64 + p] = ((int)fy & 0xffff) | ((int)fx << 16);
                    c_ly[gt * 64 + p] = ys - fy;
                    c_lx[gt * 64 + p] = xs - fx;
                }
            }
        }
    }
    __syncthreads();

    f32x4 acc[2][4];
    #pragma unroll
    for (int mi = 0; mi < 2; ++mi)
        #pragma unroll
        for (int nj = 0; nj < 4; ++nj)
            acc[mi][nj] = (f32x4)0.f;

    const unsigned short* xbase = xT + ((size_t)b * HW) * 256;
    const int ppix = q * 8 + (lane >> 3);    // S-build: this lane's pixel
    const int sl   = lane & 7;               // S-build: 8-channel slice
    const int q4   = q >> 1;
    const int mo   = (q & 1) * 2;

    // ---- prologue: build S[0] ----
    {
        int idx = ppix;                      // kc = 0, g = 0
        int yx = c_yx[idx];
        int y0 = (int)(short)(yx & 0xffff);
        int x0 = yx >> 16;
        float ly = c_ly[idx], lx = c_lx[idx];
        float omy = 1.f - ly, omx = 1.f - lx;
        float vy0 = ((unsigned)y0       < 128u) ? 1.f : 0.f;
        float vy1 = ((unsigned)(y0 + 1) < 128u) ? 1.f : 0.f;
        float vx0 = ((unsigned)x0       < 128u) ? 1.f : 0.f;
        float vx1 = ((unsigned)(x0 + 1) < 128u) ? 1.f : 0.f;
        float w00 = omy * omx * vy0 * vx0, w01 = omy * lx * vy0 * vx1;
        float w10 = ly  * omx * vy1 * vx0, w11 = ly  * lx * vy1 * vx1;
        int y0c = min(max(y0, 0), 127), y1c = min(max(y0 + 1, 0), 127);
        int x0c = min(max(x0, 0), 127), x1c = min(max(x0 + 1, 0), 127);
        const unsigned short* cb = xbase + (size_t)(sl * 8);
        bf16x8 v00 = *(const bf16x8*)(cb + (size_t)(y0c * 128 + x0c) * 256);
        bf16x8 v01 = *(const bf16x8*)(cb + (size_t)(y0c * 128 + x1c) * 256);
        bf16x8 v10 = *(const bf16x8*)(cb + (size_t)(y1c * 128 + x0c) * 256);
        bf16x8 v11 = *(const bf16x8*)(cb + (size_t)(y1c * 128 + x1c) * 256);
        float sv[8];
        #pragma unroll
        for (int e = 0; e < 8; ++e)
            sv[e] = w00 * bf2f(v00[e]) + w01 * bf2f(v01[e])
                  + w10 * bf2f(v10[e]) + w11 * bf2f(v11[e]);
        i32x4 st;
        #pragma unroll
        for (int kq = 0; kq < 4; ++kq)
            ((int*)&st)[kq] = cvt_pk_bf16(sv[kq * 2], sv[kq * 2 + 1]);
        ((i32x4*)Sbuf[0])[ppix * 8 + (sl ^ (ppix & 7))] = st;
    }
    __syncthreads();

    short* Sc = Sbuf[0];
    short* Sn = Sbuf[1];

    for (int kc = 0; kc < 36; ++kc) {
        // ---- issue next chunk's corner loads (consumed after MFMA) ----
        bf16x8 v00, v01, v10, v11;
        float w00, w01, w10, w11;
        const bool pf = (kc < 35);
        if (pf) {
            int kn = kc + 1;
            int g  = kn / 9;
            int idx = kn * 64 + ppix;
            int yx = c_yx[idx];
            int y0 = (int)(short)(yx & 0xffff);
            int x0 = yx >> 16;
            float ly = c_ly[idx], lx = c_lx[idx];
            float omy = 1.f - ly, omx = 1.f - lx;
            float vy0 = ((unsigned)y0       < 128u) ? 1.f : 0.f;
            float vy1 = ((unsigned)(y0 + 1) < 128u) ? 1.f : 0.f;
            float vx0 = ((unsigned)x0       < 128u) ? 1.f : 0.f;
            float vx1 = ((unsigned)(x0 + 1) < 128u) ? 1.f : 0.f;
            w00 = omy * omx * vy0 * vx0; w01 = omy * lx * vy0 * vx1;
            w10 = ly  * omx * vy1 * vx0; w11 = ly  * lx * vy1 * vx1;
            int y0c = min(max(y0, 0), 127), y1c = min(max(y0 + 1, 0), 127);
            int x0c = min(max(x0, 0), 127), x1c = min(max(x0 + 1, 0), 127);
            const unsigned short* cb = xbase + (size_t)(g * 64 + sl * 8);
            v00 = *(const bf16x8*)(cb + (size_t)(y0c * 128 + x0c) * 256);
            v01 = *(const bf16x8*)(cb + (size_t)(y0c * 128 + x1c) * 256);
            v10 = *(const bf16x8*)(cb + (size_t)(y1c * 128 + x0c) * 256);
            v11 = *(const bf16x8*)(cb + (size_t)(y1c * 128 + x1c) * 256);
        }
        // ---- A-fragments (global, L2-hot) + MFMA on S[cur] ----
        {
            bf16x8 a_[2][2];
            const unsigned short* wb = Wc2 + ((size_t)kc * 2048 + q4 * 512 + mo * 128 + lane) * 8;
            #pragma unroll
            for (int mi = 0; mi < 2; ++mi)
                #pragma unroll
                for (int ks = 0; ks < 2; ++ks)
                    a_[mi][ks] = *(const bf16x8*)(wb + (mi * 128 + ks * 64) * 8);
            #pragma unroll
            for (int ks = 0; ks < 2; ++ks) {
                bf16x8 bb[4];
                #pragma unroll
                for (int nj = 0; nj < 4; ++nj) {
                    int pp = nj * 16 + lr;
                    bb[nj] = *(const bf16x8*)&((const i32x4*)Sc)[pp * 8 + ((ks * 4 + lq) ^ (pp & 7))];
                }
                #pragma unroll
                for (int mi = 0; mi < 2; ++mi)
                    #pragma unroll
                    for (int nj = 0; nj < 4; ++nj)
                        acc[mi][nj] = __builtin_amdgcn_mfma_f32_16x16x32_bf16(
                            a_[mi][ks], bb[nj], acc[mi][nj], 0, 0, 0);
            }
        }
        // ---- consume corner loads: interp + cvt + write S[next] ----
        if (pf) {
            float sv[8];
            #pragma unroll
            for (int e = 0; e < 8; ++e)
                sv[e] = w00 * bf2f(v00[e]) + w01 * bf2f(v01[e])
                      + w10 * bf2f(v10[e]) + w11 * bf2f(v11[e]);
            i32x4 st;
            #pragma unroll
            for (int kq = 0; kq < 4; ++kq)
                ((int*)&st)[kq] = cvt_pk_bf16(sv[kq * 2], sv[kq * 2 + 1]);
            ((i32x4*)Sn)[ppix * 8 + (sl ^ (ppix & 7))] = st;
        }
        __syncthreads();
        short* tmp = Sc; Sc = Sn; Sn = tmp;
    }

    // ---- epilogue: ReLU + store ----
    #pragma unroll
    for (int mi = 0; mi < 2; ++mi)
        #pragma unroll
        for (int nj = 0; nj < 4; ++nj)
            #pragma unroll
            for (int r = 0; r < 4; ++r) {
                int o  = q * 32 + mi * 16 + lq * 4 + r;
                int pp = nj * 16 + lr;
                out[((size_t)(b * 256 + o) << 14) + hw0 + pp] = fmaxf(acc[mi][nj][r], 0.f);
            }
}

extern "C" void kernel_launch(void* const* d_in, const int* in_sizes, int n_in,
                              void* d_out, int out_size, void* d_ws, size_t ws_size,
                              hipStream_t stream) {
    const float* x     = (const float*)d_in[0];   // [2,256,128,128]
    const float* w_off = (const float*)d_in[1];   // [72,256,1,1]
    const float* b_off = (const float*)d_in[2];   // [72]
    const float* w_def = (const float*)d_in[3];   // [256,256,3,3]
    float* out = (float*)d_out;

    unsigned short* xT  = (unsigned short*)d_ws;                     // 16.78 MB
    unsigned short* Wc2 = (unsigned short*)((char*)d_ws + 16777216); // 1.18 MB
    unsigned short* Wo2 = (unsigned short*)((char*)d_ws + 17956864); // 40 KB

    prep_kernel<<<2346, 256, 0, stream>>>(x, w_def, w_off, xT, Wc2, Wo2);
    deform_kernel<<<512, 512, 0, stream>>>(xT, Wc2, Wo2, b_off, out);
}

// Round 6
// 148.532 us; speedup vs baseline: 9.9656x; 1.0936x over previous
//
#include <hip/hip_runtime.h>

#define HW 16384

typedef _Float16 f16;
typedef __attribute__((ext_vector_type(4))) float f32x4;
typedef __attribute__((ext_vector_type(8))) _Float16 f16x8;
typedef __attribute__((ext_vector_type(4))) int i32x4;

union h8i4 { f16x8 h; i32x4 i; };

static __device__ __forceinline__ int pk_f16(float lo, float hi) {
    int r;
    asm("v_cvt_pkrtz_f16_f32 %0, %1, %2" : "=v"(r) : "v"(lo), "v"(hi));
    return r;
}
static __device__ __forceinline__ f16 ush2h(unsigned short u) {
    union { unsigned short s; f16 h; } c; c.s = u; return c.h;
}

// ---------------- prep: transpose x -> NHWC f16, weights -> fragment order ----------------
__global__ __launch_bounds__(256) void prep_kernel(
    const float* __restrict__ x, const float* __restrict__ wd,
    const float* __restrict__ woff,
    f16* __restrict__ xT, f16* __restrict__ Wc2, f16* __restrict__ Wo2)
{
    int bid = blockIdx.x;
    int tid = threadIdx.x;
    if (bid < 2048) {
        __shared__ float tl[64][65];
        int ct = bid & 3, pt = (bid >> 2) & 255, b = bid >> 10;
        const float* xb = x + ((size_t)(b * 256 + ct * 64)) * HW + pt * 64;
        #pragma unroll
        for (int j = 0; j < 4; ++j) {
            int slot = tid + j * 256;            // 1024 = 64 ch * 16 quads
            int c = slot >> 4, p4 = slot & 15;
            float4 v = *(const float4*)(xb + (size_t)c * HW + p4 * 4);
            tl[c][p4 * 4 + 0] = v.x;
            tl[c][p4 * 4 + 1] = v.y;
            tl[c][p4 * 4 + 2] = v.z;
            tl[c][p4 * 4 + 3] = v.w;
        }
        __syncthreads();
        f16* ob = xT + ((size_t)(b * HW + pt * 64)) * 256 + ct * 64;
        #pragma unroll
        for (int j2 = 0; j2 < 2; ++j2) {
            int slot = tid + j2 * 256;           // 512 = 64 pix * 8 slices
            int p = slot >> 3, sl = slot & 7;
            i32x4 st;
            #pragma unroll
            for (int kq = 0; kq < 4; ++kq)
                ((int*)&st)[kq] = pk_f16(tl[sl*8 + kq*2][p], tl[sl*8 + kq*2 + 1][p]);
            *(i32x4*)(ob + (size_t)p * 256 + sl * 8) = st;
        }
    } else if (bid < 2336) {
        // slot = kc*2048 + q4*512 + mi*128 + ks*64 + lane ; 8 f16 each
        int slot = (bid - 2048) * 256 + tid;     // 0..73727
        int l  = slot & 63;
        int ks = (slot >> 6) & 1;
        int mi = (slot >> 7) & 3;
        int q4 = (slot >> 9) & 3;
        int kc = slot >> 11;                     // 0..35 = g*9+tap
        int g = kc / 9, tap = kc - g * 9;
        int o = q4 * 64 + mi * 16 + (l & 15);
        int cgb = (ks * 4 + (l >> 4)) * 8;
        f16* dst = Wc2 + (size_t)slot * 8;
        const float* src = wd + (size_t)o * 2304 + tap;
        #pragma unroll
        for (int e = 0; e < 8; ++e)
            dst[e] = (f16)(src[(size_t)(g * 64 + cgb + e) * 9]);
    } else {
        int slot = (bid - 2336) * 256 + tid;     // 0..2559 b128 slots
        int kk = slot / 320;
        int rem = slot - kk * 320;
        int o = rem >> 2, jq = rem & 3;
        f16* dst = Wo2 + (size_t)slot * 8;
        #pragma unroll
        for (int e = 0; e < 8; ++e)
            dst[e] = (o < 72) ? (f16)(woff[(size_t)o * 256 + kk * 32 + jq * 8 + e]) : (f16)0.f;
    }
}

// ---------------- main: fused offsets (MFMA) + deformable conv (MFMA, pipelined) + ReLU ----------------
__global__ __launch_bounds__(512, 4) void deform_kernel(
    const f16* __restrict__ xT, const f16* __restrict__ Wc2,
    const f16* __restrict__ Wo2, const float* __restrict__ b_off,
    float* __restrict__ out)
{
    __shared__ __align__(16) i32x4 pk[2304];        // {idx00, idx11, pk(w00,w01), pk(w10,w11)}
    __shared__ __align__(16) short Sbuf[2][4096];   // double-buffered S tile [64 pix][64 ch] f16

    const int t    = threadIdx.x;
    const int lane = t & 63;
    const int q    = t >> 6;                 // wave 0..7
    const int lr   = lane & 15, lq = lane >> 4;
    int bid = blockIdx.x;
    bid = (bid & 7) * 64 + (bid >> 3);       // XCD-aware swizzle (512 % 8 == 0)
    const int gp0  = bid << 6;
    const int b    = gp0 >> 14;
    const int hw0  = gp0 & 16383;
    const int h    = hw0 >> 7;
    const int w0   = hw0 & 127;

    // ---- phase 1: 72 offset channels via MFMA; pack geometry into pk[] ----
    {
        const int p16 = (q & 3) * 16;
        f16x8 xv[8];
        const f16* xrow = xT + ((size_t)(b * HW + hw0 + p16 + lr)) * 256 + lq * 8;
        #pragma unroll
        for (int kk = 0; kk < 8; ++kk)
            xv[kk] = *(const f16x8*)(xrow + kk * 32);
        const int mi0 = (q < 4) ? 0 : 3;
        const int nmi = (q < 4) ? 3 : 2;
        for (int im = 0; im < nmi; ++im) {
            int mi = mi0 + im;
            f32x4 oa = (f32x4)0.f;
            #pragma unroll
            for (int kk = 0; kk < 8; ++kk) {
                f16x8 af = *(const f16x8*)(Wo2 + (size_t)((kk * 80 + mi * 16 + lr) * 32 + lq * 8));
                oa = __builtin_amdgcn_mfma_f32_16x16x32_f16(af, xv[kk], oa, 0, 0, 0);
            }
            #pragma unroll
            for (int ri = 0; ri < 2; ++ri) {
                int gt = mi * 8 + lq * 2 + ri;
                if (gt < 36) {
                    int p = p16 + lr;
                    float dy = oa[ri * 2]     + b_off[2 * gt];
                    float dx = oa[ri * 2 + 1] + b_off[2 * gt + 1];
                    int tap = gt % 9;
                    float ys = (float)(h - 1 + tap / 3) + dy;
                    float xs = (float)(w0 + p - 1 + tap % 3) + dx;
                    float fy = floorf(ys), fx = floorf(xs);
                    int y0 = (int)fy, x0 = (int)fx;
                    float ly = ys - fy, lx = xs - fx;
                    float omy = 1.f - ly, omx = 1.f - lx;
                    float vy0 = ((unsigned)y0       < 128u) ? 1.f : 0.f;
                    float vy1 = ((unsigned)(y0 + 1) < 128u) ? 1.f : 0.f;
                    float vx0 = ((unsigned)x0       < 128u) ? 1.f : 0.f;
                    float vx1 = ((unsigned)(x0 + 1) < 128u) ? 1.f : 0.f;
                    int y0c = min(max(y0, 0), 127), y1c = min(max(y0 + 1, 0), 127);
                    int x0c = min(max(x0, 0), 127), x1c = min(max(x0 + 1, 0), 127);
                    i32x4 e;
                    e.x = y0c * 128 + x0c;
                    e.y = y1c * 128 + x1c;
                    e.z = pk_f16(omy * omx * vy0 * vx0, omy * lx * vy0 * vx1);
                    e.w = pk_f16(ly  * omx * vy1 * vx0, ly  * lx * vy1 * vx1);
                    pk[gt * 64 + p] = e;
                }
            }
        }
    }
    __syncthreads();

    f32x4 acc[2][4];
    #pragma unroll
    for (int mi = 0; mi < 2; ++mi)
        #pragma unroll
        for (int nj = 0; nj < 4; ++nj)
            acc[mi][nj] = (f32x4)0.f;

    const f16* xbase = xT + ((size_t)b * HW) * 256;
    const int ppix = q * 8 + (lane >> 3);    // S-build: this lane's pixel
    const int sl   = lane & 7;               // S-build: 8-channel slice
    const int q4   = q >> 1;
    const int mo   = (q & 1) * 2;

    // ---- prologue: build S[0] (kc = 0, g = 0) ----
    {
        i32x4 cd = pk[ppix];
        int idx00 = cd.x, idx11 = cd.y;
        int idx01 = (idx00 & ~127) | (idx11 & 127);
        int idx10 = (idx11 & ~127) | (idx00 & 127);
        f16x8 w00v = (f16x8)ush2h((unsigned short)(cd.z & 0xffff));
        f16x8 w01v = (f16x8)ush2h((unsigned short)((unsigned)cd.z >> 16));
        f16x8 w10v = (f16x8)ush2h((unsigned short)(cd.w & 0xffff));
        f16x8 w11v = (f16x8)ush2h((unsigned short)((unsigned)cd.w >> 16));
        const f16* cb = xbase + sl * 8;
        f16x8 sv = *(const f16x8*)(cb + (size_t)idx00 * 256) * w00v;
        sv += *(const f16x8*)(cb + (size_t)idx01 * 256) * w01v;
        sv += *(const f16x8*)(cb + (size_t)idx10 * 256) * w10v;
        sv += *(const f16x8*)(cb + (size_t)idx11 * 256) * w11v;
        h8i4 u; u.h = sv;
        ((i32x4*)Sbuf[0])[ppix * 8 + (sl ^ (ppix & 7))] = u.i;
    }
    __syncthreads();

    short* Sc = Sbuf[0];
    short* Sn = Sbuf[1];

    for (int kc = 0; kc < 36; ++kc) {
        // ---- issue next chunk's corner loads (consumed after MFMA) ----
        f16x8 v00, v01, v10, v11;
        f16x8 w00v, w01v, w10v, w11v;
        const bool pf = (kc < 35);
        if (pf) {
            int kn = kc + 1;
            int g  = kn / 9;
            i32x4 cd = pk[kn * 64 + ppix];
            int idx00 = cd.x, idx11 = cd.y;
            int idx01 = (idx00 & ~127) | (idx11 & 127);
            int idx10 = (idx11 & ~127) | (idx00 & 127);
            w00v = (f16x8)ush2h((unsigned short)(cd.z & 0xffff));
            w01v = (f16x8)ush2h((unsigned short)((unsigned)cd.z >> 16));
            w10v = (f16x8)ush2h((unsigned short)(cd.w & 0xffff));
            w11v = (f16x8)ush2h((unsigned short)((unsigned)cd.w >> 16));
            const f16* cb = xbase + (size_t)(g * 64 + sl * 8);
            v00 = *(const f16x8*)(cb + (size_t)idx00 * 256);
            v01 = *(const f16x8*)(cb + (size_t)idx01 * 256);
            v10 = *(const f16x8*)(cb + (size_t)idx10 * 256);
            v11 = *(const f16x8*)(cb + (size_t)idx11 * 256);
        }
        // ---- A-fragments (global, L2-hot) + MFMA on S[cur] ----
        {
            f16x8 a_[2][2];
            const f16* wb = Wc2 + ((size_t)kc * 2048 + q4 * 512 + mo * 128 + lane) * 8;
            #pragma unroll
            for (int mi = 0; mi < 2; ++mi)
                #pragma unroll
                for (int ks = 0; ks < 2; ++ks)
                    a_[mi][ks] = *(const f16x8*)(wb + (mi * 128 + ks * 64) * 8);
            #pragma unroll
            for (int ks = 0; ks < 2; ++ks) {
                f16x8 bb[4];
                #pragma unroll
                for (int nj = 0; nj < 4; ++nj) {
                    int pp = nj * 16 + lr;
                    h8i4 u;
                    u.i = ((const i32x4*)Sc)[pp * 8 + ((ks * 4 + lq) ^ (pp & 7))];
                    bb[nj] = u.h;
                }
                #pragma unroll
                for (int mi = 0; mi < 2; ++mi)
                    #pragma unroll
                    for (int nj = 0; nj < 4; ++nj)
                        acc[mi][nj] = __builtin_amdgcn_mfma_f32_16x16x32_f16(
                            a_[mi][ks], bb[nj], acc[mi][nj], 0, 0, 0);
            }
        }
        // ---- consume corner loads: packed interp + write S[next] ----
        if (pf) {
            f16x8 sv = v00 * w00v;
            sv += v01 * w01v;
            sv += v10 * w10v;
            sv += v11 * w11v;
            h8i4 u; u.h = sv;
            ((i32x4*)Sn)[ppix * 8 + (sl ^ (ppix & 7))] = u.i;
        }
        __syncthreads();
        short* tmp = Sc; Sc = Sn; Sn = tmp;
    }

    // ---- epilogue: ReLU + store ----
    #pragma unroll
    for (int mi = 0; mi < 2; ++mi)
        #pragma unroll
        for (int nj = 0; nj < 4; ++nj)
            #pragma unroll
            for (int r = 0; r < 4; ++r) {
                int o  = q * 32 + mi * 16 + lq * 4 + r;
                int pp = nj * 16 + lr;
                out[((size_t)(b * 256 + o) << 14) + hw0 + pp] = fmaxf(acc[mi][nj][r], 0.f);
            }
}

extern "C" void kernel_launch(void* const* d_in, const int* in_sizes, int n_in,
                              void* d_out, int out_size, void* d_ws, size_t ws_size,
                              hipStream_t stream) {
    const float* x     = (const float*)d_in[0];   // [2,256,128,128]
    const float* w_off = (const float*)d_in[1];   // [72,256,1,1]
    const float* b_off = (const float*)d_in[2];   // [72]
    const float* w_def = (const float*)d_in[3];   // [256,256,3,3]
    float* out = (float*)d_out;

    f16* xT  = (f16*)d_ws;                     // 16.78 MB
    f16* Wc2 = (f16*)((char*)d_ws + 16777216); // 1.18 MB
    f16* Wo2 = (f16*)((char*)d_ws + 17956864); // 40 KB

    prep_kernel<<<2346, 256, 0, stream>>>(x, w_def, w_off, xT, Wc2, Wo2);
    deform_kernel<<<512, 512, 0, stream>>>(xT, Wc2, Wo2, b_off, out);
}